// Round 1
// baseline (18975.441 us; speedup 1.0000x reference)
//
#include <hip/hip_runtime.h>

// ============================================================================
// 2-layer GRU RNN, persistent cooperative kernel.
//   B=64, S=512, I=512, H=1024, O=2.
// Design:
//  - fp16 weights resident in LDS (per-WG 8-column slice of 3 gates, 1 layer)
//  - fp16 activations (fp32 master h), fp32 MFMA accumulation (16x16x32_f16)
//  - software pipeline: iter i runs L0@t=i and L1@t=i-1 -> 2 grid barriers/step
//  - hand-rolled device-scope sense-reversing barrier in workspace
// ============================================================================

typedef _Float16 f16;
typedef f16  f16x8 __attribute__((ext_vector_type(8)));
typedef float f32x4 __attribute__((ext_vector_type(4)));

#define NB   64
#define SEQ  512
#define IDIM 512
#define HDIM 1024

// workspace layout (bytes)
#define OFF_H0   0u                      // f16 [2][64][1024]  = 262144
#define OFF_H1   262144u                 // f16 [2][64][1024]
#define OFF_H0R  524288u                 // f16 [64][1024]     = 131072
#define OFF_H1R  655360u                 // f16 [64][1024]
#define OFF_H0F  786432u                 // f32 [64][1024]     = 262144
#define OFF_H1F  1048576u                // f32 [64][1024]
#define OFF_BAR  1310720u                // barrier counters (256 B)
#define OFF_X16  1310976u                // f16 [512][64][512] = 33554432
#define SMEM_BYTES (3*8*(2*HDIM+8)*2)    // 98688

__device__ __forceinline__ float sigf(float x){ return 1.0f/(1.0f+__expf(-x)); }
__device__ __forceinline__ float tanh_fast(float x){ float e=__expf(2.0f*x); return 1.0f - 2.0f/(e+1.0f); }

// device-scope sense-reversing barrier; cnt and gen on separate lines
__device__ __forceinline__ void grid_barrier(unsigned* cnt, unsigned* gen,
                                             unsigned nwg, unsigned& lgen){
  __syncthreads();
  if (threadIdx.x == 0){
    unsigned old = __hip_atomic_fetch_add(cnt, 1u, __ATOMIC_ACQ_REL, __HIP_MEMORY_SCOPE_AGENT);
    if (old == nwg - 1u){
      __hip_atomic_store(cnt, 0u, __ATOMIC_RELAXED, __HIP_MEMORY_SCOPE_AGENT);
      __hip_atomic_fetch_add(gen, 1u, __ATOMIC_ACQ_REL, __HIP_MEMORY_SCOPE_AGENT);
    } else {
      while (__hip_atomic_load(gen, __ATOMIC_RELAXED, __HIP_MEMORY_SCOPE_AGENT) == lgen){
        __builtin_amdgcn_s_sleep(1);
      }
      (void)__hip_atomic_load(gen, __ATOMIC_ACQUIRE, __HIP_MEMORY_SCOPE_AGENT);
    }
    lgen++;
  }
  __syncthreads();
}

// Dual-gate GEMM inner loop for one wave's 16-row m-tile.
// A fragments from global (two pieces, lane-adjusted base ptrs, +64B per kstep),
// B fragments from LDS (lane-adjusted, +64B per kstep, continuous across pieces).
template<int NG, int NK1, int NK2>
__device__ __forceinline__ void dual_gemm(const char* a1, const char* a2,
                                          const char* b0, const char* b1,
                                          f32x4& acc0, f32x4& acc1){
  constexpr int NK = NK1 + NK2;
  constexpr int NC = NK/8;
  f16x8 abuf[2][8];
#pragma unroll
  for (int j=0;j<8;++j){
    const char* p = (j < NK1) ? (a1 + j*64) : (a2 + (j-NK1)*64);
    abuf[0][j] = *(const f16x8*)p;
  }
#pragma unroll
  for (int c=0;c<NC;++c){
    if (c+1 < NC){
#pragma unroll
      for (int j=0;j<8;++j){
        int ks=(c+1)*8+j;
        const char* p = (ks < NK1) ? (a1 + ks*64) : (a2 + (ks-NK1)*64);
        abuf[(c+1)&1][j] = *(const f16x8*)p;
      }
    }
#pragma unroll
    for (int j=0;j<8;++j){
      int ks = c*8+j;
      f16x8 av = abuf[c&1][j];
      f16x8 b0v = *(const f16x8*)(b0 + ks*64);
      acc0 = __builtin_amdgcn_mfma_f32_16x16x32_f16(av, b0v, acc0, 0,0,0);
      if (NG==2){
        f16x8 b1v = *(const f16x8*)(b1 + ks*64);
        acc1 = __builtin_amdgcn_mfma_f32_16x16x32_f16(av, b1v, acc1, 0,0,0);
      }
    }
  }
}

template<int LAYER>
__device__ void run_rnn(int idx,
    const float* Wr, const float* brp, const float* Wz, const float* bzp,
    const float* Wc, const float* bcp, char* ws, f16* wlds, unsigned* bar){
  constexpr int K  = (LAYER==0) ? (IDIM+HDIM) : (2*HDIM);   // 1536 / 2048
  constexpr int RS = K + 8;                                  // LDS row stride (pad 16B)
  const int n0  = idx*8;
  const int tid = threadIdx.x;

  // ---- load fp16 weight slice into LDS (rows n0..n0+7, all K, 3 gates) ----
  for (int g=0; g<3; ++g){
    const float* W = (g==0)? Wr : (g==1)? Wz : Wc;
#pragma unroll 1
    for (int e = tid; e < 8*K; e += 256){
      int r = e / K, k = e - r*K;
      wlds[(size_t)g*8*RS + (size_t)r*RS + k] = (f16)W[(size_t)(n0+r)*K + k];
    }
  }
  __syncthreads();

  const int lane = tid & 63;
  const int wv   = tid >> 6;          // m-tile index (rows 16*wv .. +15)
  const int quad = lane >> 4;
  const int ncol = lane & 15;
  const int nloc = ncol & 7;
  const int col  = n0 + nloc;
  const bool valid = (ncol < 8);
  const int m0 = wv*16;

  const float brv = brp[col], bzv = bzp[col], bcv = bcp[col];

  f16*   h0_16 = (f16*)(ws + OFF_H0);
  f16*   h1_16 = (f16*)(ws + OFF_H1);
  f16*   h0r   = (f16*)(ws + OFF_H0R);
  f16*   h1r   = (f16*)(ws + OFF_H1R);
  float* hf    = (float*)(ws + (LAYER==0 ? OFF_H0F : OFF_H1F));
  const f16* x16 = (const f16*)(ws + OFF_X16);
  f16*   hr      = (LAYER==0) ? h0r : h1r;
  f16*   h16own  = (LAYER==0) ? h0_16 : h1_16;

  // lane-local element offsets into A matrices
  const int a_off_x = (m0 + ncol)*IDIM + quad*8;
  const int a_off_h = (m0 + ncol)*HDIM + quad*8;
  const size_t b_off = (size_t)nloc*RS + quad*8;
  const char* bl0 = (const char*)(wlds + 0*8*(size_t)RS + b_off);
  const char* bl1 = (const char*)(wlds + 1*8*(size_t)RS + b_off);
  const char* bl2 = (const char*)(wlds + 2*8*(size_t)RS + b_off);

  unsigned lgen = 0;
  float zreg[4] = {0,0,0,0};

  for (int iter = 0; iter <= SEQ; ++iter){
    const int  t    = (LAYER==0) ? iter : (iter-1);
    const bool act  = (LAYER==0) ? (iter < SEQ) : (iter >= 1);
    const int  bufA = (iter & 1) ^ 1;     // buffer holding H0[t_needed]

    // ---------------- PHASE A : pre_r, pre_z ----------------
    f32x4 accr = {0,0,0,0}, accz = {0,0,0,0};
    if (act){
      if (LAYER==0){
        const char* a1 = (const char*)(x16 + (size_t)t*NB*IDIM + a_off_x);
        const char* a2 = (const char*)(h0_16 + (size_t)bufA*NB*HDIM + a_off_h);
        dual_gemm<2,16,32>(a1,a2,bl0,bl1,accr,accz);
      } else {
        const char* a1 = (const char*)(h0_16 + (size_t)bufA*NB*HDIM + a_off_h);
        const char* a2 = (const char*)(h1_16 + (size_t)(iter&1)*NB*HDIM + a_off_h);
        dual_gemm<2,32,32>(a1,a2,bl0,bl1,accr,accz);
      }
#pragma unroll
      for (int i=0;i<4;++i){
        int m = m0 + quad*4 + i;
        float r = sigf(accr[i] + brv);
        float z = sigf(accz[i] + bzv);
        zreg[i] = z;
        if (valid){
          float hold = hf[(size_t)m*HDIM + col];
          hr[(size_t)m*HDIM + col] = (f16)(hold * r);
        }
      }
    }
    grid_barrier(bar, bar+32, 256u, lgen);

    // ---------------- PHASE B : candidate + h update ----------------
    if (act){
      f32x4 accc = {0,0,0,0}, dum = {0,0,0,0};
      if (LAYER==0){
        const char* a1 = (const char*)(x16 + (size_t)t*NB*IDIM + a_off_x);
        const char* a2 = (const char*)(h0r + a_off_h);
        dual_gemm<1,16,32>(a1,a2,bl2,bl2,accc,dum);
      } else {
        const char* a1 = (const char*)(h0_16 + (size_t)bufA*NB*HDIM + a_off_h);
        const char* a2 = (const char*)(h1r + a_off_h);
        dual_gemm<1,32,32>(a1,a2,bl2,bl2,accc,dum);
      }
      const int bufW = (LAYER==0) ? (iter&1) : ((iter&1)^1);
#pragma unroll
      for (int i=0;i<4;++i){
        int m = m0 + quad*4 + i;
        float can = tanh_fast(accc[i] + bcv);
        if (valid){
          size_t o = (size_t)m*HDIM + col;
          float hold = hf[o];
          float hnew = hold*zreg[i] + (1.0f - zreg[i])*can;
          hf[o] = hnew;
          h16own[(size_t)bufW*NB*HDIM + o] = (f16)hnew;
        }
      }
    }
    grid_barrier(bar, bar+32, 256u, lgen);
  }
}

__global__ void __launch_bounds__(256, 1)
rnn_kernel(const float* x,
           const float* Wr0, const float* br0, const float* Wz0, const float* bz0,
           const float* Wc0, const float* bc0,
           const float* Wr1, const float* br1, const float* Wz1, const float* bz1,
           const float* Wc1, const float* bc1,
           const float* Wreg, const float* breg,
           float* out, char* ws){
  extern __shared__ char smem[];
  f16* wlds = (f16*)smem;
  unsigned* bar = (unsigned*)(ws + OFF_BAR);
  const int layer = blockIdx.x & 1;
  const int idx   = blockIdx.x >> 1;

  if (layer==0) run_rnn<0>(idx, Wr0,br0,Wz0,bz0,Wc0,bc0, ws, wlds, bar);
  else          run_rnn<1>(idx, Wr1,br1,Wz1,bz1,Wc1,bc1, ws, wlds, bar);

  // final regressor: out[m][o] = h1[m] . Wreg[o] + breg[o]
  if (blockIdx.x == 0){
    const float* h1f = (const float*)(ws + OFF_H1F);
    int t2 = threadIdx.x;
    if (t2 < NB*2){
      int m = t2 >> 1, o = t2 & 1;
      const float* hp = h1f + (size_t)m*HDIM;
      const float* wp = Wreg + (size_t)o*HDIM;
      float acc = 0.f;
#pragma unroll 4
      for (int k=0;k<HDIM;k+=4){
        acc += hp[k]*wp[k] + hp[k+1]*wp[k+1] + hp[k+2]*wp[k+2] + hp[k+3]*wp[k+3];
      }
      out[t2] = acc + breg[o];
    }
  }
}

// x [B][S][I] fp32  ->  x16 [S][B][I] fp16
__global__ void prep_x(const float* x, f16* x16){
  size_t i = (size_t)blockIdx.x*256 + threadIdx.x;
  int ii = (int)(i & (IDIM-1));
  size_t r = i >> 9;            // = s*64 + b
  int b = (int)(r & (NB-1));
  int s = (int)(r >> 6);
  x16[i] = (f16)x[((size_t)b*SEQ + s)*IDIM + ii];
}

extern "C" void kernel_launch(void* const* d_in, const int* in_sizes, int n_in,
                              void* d_out, int out_size, void* d_ws, size_t ws_size,
                              hipStream_t stream){
  const float* x    = (const float*)d_in[0];
  const float* Wr0  = (const float*)d_in[1];
  const float* br0  = (const float*)d_in[2];
  const float* Wz0  = (const float*)d_in[3];
  const float* bz0  = (const float*)d_in[4];
  const float* Wc0  = (const float*)d_in[5];
  const float* bc0  = (const float*)d_in[6];
  const float* Wr1  = (const float*)d_in[7];
  const float* br1  = (const float*)d_in[8];
  const float* Wz1  = (const float*)d_in[9];
  const float* bz1  = (const float*)d_in[10];
  const float* Wc1  = (const float*)d_in[11];
  const float* bc1  = (const float*)d_in[12];
  const float* Wreg = (const float*)d_in[13];
  const float* breg = (const float*)d_in[14];
  float* out = (float*)d_out;
  char*  ws  = (char*)d_ws;

  // zero h buffers + barrier counters (first 1,310,976 bytes)
  hipMemsetAsync(ws, 0, OFF_BAR + 256, stream);

  // convert x to fp16, [S][B][I]
  prep_x<<<(SEQ*NB*IDIM)/256, 256, 0, stream>>>(x, (f16*)(ws + OFF_X16));

  // allow >64KB dynamic LDS
  hipFuncSetAttribute((const void*)rnn_kernel,
                      hipFuncAttributeMaxDynamicSharedMemorySize, 160*1024);

  void* args[] = { (void*)&x,
                   (void*)&Wr0, (void*)&br0, (void*)&Wz0, (void*)&bz0,
                   (void*)&Wc0, (void*)&bc0,
                   (void*)&Wr1, (void*)&br1, (void*)&Wz1, (void*)&bz1,
                   (void*)&Wc1, (void*)&bc1,
                   (void*)&Wreg, (void*)&breg,
                   (void*)&out, (void*)&ws };
  hipLaunchCooperativeKernel((const void*)rnn_kernel, dim3(256), dim3(256),
                             args, (unsigned)SMEM_BYTES, stream);
}

// Round 2
// 18037.120 us; speedup vs baseline: 1.0520x; 1.0520x over previous
//
#include <hip/hip_runtime.h>

// ============================================================================
// 2-layer GRU RNN, persistent cooperative kernel. B=64, S=512, I=512, H=1024.
// Round 2:
//  - 512 thr/WG (8 waves = 2/SIMD): wave = (m-tile 0..3) x (k-half 0..1)
//  - K-split partials combined via LDS scratch; group0 waves do epilogues
//  - A-slice fully prefetched into VGPRs + sched_barrier(0) to pin the loads
//  - B weights in LDS in MFMA-fragment order [gate][kstep][lane*16B] -> no
//    bank conflicts (lanes l, l+8 broadcast same address)
// ============================================================================

typedef _Float16 f16;
typedef f16  f16x8 __attribute__((ext_vector_type(8)));
typedef float f32x4 __attribute__((ext_vector_type(4)));

#define NB   64
#define SEQ  512
#define IDIM 512
#define HDIM 1024

// workspace layout (bytes)
#define OFF_H0   0u                      // f16 [2][64][1024]  = 262144
#define OFF_H1   262144u                 // f16 [2][64][1024]
#define OFF_H0R  524288u                 // f16 [64][1024]     = 131072
#define OFF_H1R  655360u                 // f16 [64][1024]
#define OFF_H0F  786432u                 // f32 [64][1024]     = 262144
#define OFF_H1F  1048576u                // f32 [64][1024]
#define OFF_BAR  1310720u                // barrier counters (256 B)
#define OFF_X16  1310976u                // f16 [512][64][512] = 33554432

// LDS: weights (3 gates, frag order, 512B/kstep) + 8KB reduction scratch
#define SMEM_BYTES (3*64*512 + 8192)     // 106496 (L1 worst case)

__device__ __forceinline__ float sigf(float x){ return 1.0f/(1.0f+__expf(-x)); }
__device__ __forceinline__ float tanh_fast(float x){ float e=__expf(2.0f*x); return 1.0f - 2.0f/(e+1.0f); }

__device__ __forceinline__ void grid_barrier(unsigned* cnt, unsigned* gen,
                                             unsigned nwg, unsigned& lgen){
  __syncthreads();
  if (threadIdx.x == 0){
    unsigned old = __hip_atomic_fetch_add(cnt, 1u, __ATOMIC_ACQ_REL, __HIP_MEMORY_SCOPE_AGENT);
    if (old == nwg - 1u){
      __hip_atomic_store(cnt, 0u, __ATOMIC_RELAXED, __HIP_MEMORY_SCOPE_AGENT);
      __hip_atomic_fetch_add(gen, 1u, __ATOMIC_ACQ_REL, __HIP_MEMORY_SCOPE_AGENT);
    } else {
      while (__hip_atomic_load(gen, __ATOMIC_RELAXED, __HIP_MEMORY_SCOPE_AGENT) == lgen){
        __builtin_amdgcn_s_sleep(1);
      }
      (void)__hip_atomic_load(gen, __ATOMIC_ACQUIRE, __HIP_MEMORY_SCOPE_AGENT);
    }
    lgen++;
  }
  __syncthreads();
}

// GEMM for one wave: NK1 ksteps from a1, NK2 from a2 (each kstep = 64B stride
// in A, 512B stride in LDS-B frag layout). All A loads issued up front and
// pinned above the MFMA loop by sched_barrier.
template<int NG, int NK1, int NK2>
__device__ __forceinline__ void gemm_frag(const char* a1, const char* a2,
                                          const char* b0, const char* b1,
                                          f32x4& acc0, f32x4& acc1){
  constexpr int NKT = NK1 + NK2;
  f16x8 a[NKT];
#pragma unroll
  for (int j=0;j<NK1;++j) a[j] = *(const f16x8*)(a1 + j*64);
#pragma unroll
  for (int j=0;j<NK2;++j) a[NK1+j] = *(const f16x8*)(a2 + j*64);
  __builtin_amdgcn_sched_barrier(0);
#pragma unroll
  for (int ks=0; ks<NKT; ++ks){
    f16x8 b0v = *(const f16x8*)(b0 + ks*512);
    acc0 = __builtin_amdgcn_mfma_f32_16x16x32_f16(a[ks], b0v, acc0, 0,0,0);
    if constexpr (NG==2){
      f16x8 b1v = *(const f16x8*)(b1 + ks*512);
      acc1 = __builtin_amdgcn_mfma_f32_16x16x32_f16(a[ks], b1v, acc1, 0,0,0);
    }
  }
}

template<int LAYER>
__device__ void run_rnn(int idx,
    const float* Wr, const float* brp, const float* Wz, const float* bzp,
    const float* Wc, const float* bcp, char* ws, char* smem, unsigned* bar){
  constexpr int K   = (LAYER==0) ? (IDIM+HDIM) : (2*HDIM);   // 1536 / 2048
  constexpr int NKS = K/32;                                   // 48 / 64
  constexpr int GS  = NKS*256;                                // f16 per gate
  const int n0  = idx*8;
  const int tid = threadIdx.x;

  f16*   wl = (f16*)smem;
  float* sc = (float*)(smem + (size_t)3*GS*2);   // [8][4][64] f32 scratch

  // ---- weights -> LDS in MFMA frag order: wl[g][gk][quad][nloc][e] ----
  for (int g=0; g<3; ++g){
    const float* W = (g==0)? Wr : (g==1)? Wz : Wc;
#pragma unroll 1
    for (int i = tid; i < GS; i += 512){
      int gk   = i >> 8;
      int rem  = i & 255;
      int quad = rem >> 6;
      int rem2 = rem & 63;
      int nl   = rem2 >> 3;
      int e    = rem2 & 7;
      wl[(size_t)g*GS + i] = (f16)W[(size_t)(n0+nl)*K + gk*32 + quad*8 + e];
    }
  }
  __syncthreads();

  const int lane = tid & 63;
  const int wv   = tid >> 6;          // 0..7
  const int mt   = wv & 3;            // m-tile index
  const int kg   = wv >> 2;           // k-group
  const int m0   = mt*16;
  const int quad = lane >> 4;
  const int ncol = lane & 15;
  const int nloc = ncol & 7;
  const int col  = n0 + nloc;
  const bool valid = (ncol < 8);

  const float brv = brp[col], bzv = bzp[col], bcv = bcp[col];

  f16*   h0_16 = (f16*)(ws + OFF_H0);
  f16*   h1_16 = (f16*)(ws + OFF_H1);
  f16*   h0r   = (f16*)(ws + OFF_H0R);
  f16*   h1r   = (f16*)(ws + OFF_H1R);
  float* hf    = (float*)(ws + (LAYER==0 ? OFF_H0F : OFF_H1F));
  const f16* x16 = (const f16*)(ws + OFF_X16);
  f16*   hr      = (LAYER==0) ? h0r : h1r;
  f16*   h16own  = (LAYER==0) ? h0_16 : h1_16;

  const int a_off_x = (m0 + ncol)*IDIM + quad*8;
  const int a_off_h = (m0 + ncol)*HDIM + quad*8;

  // B frag base (lane part): byte addr quad*128 + nloc*16; gate g adds g*GS*2;
  // k-group adds gk0*512.
  const size_t b_lane = (size_t)quad*128 + (size_t)nloc*16;
  const char* bl0 = smem + 0*(size_t)GS*2 + b_lane;
  const char* bl1 = smem + 1*(size_t)GS*2 + b_lane;
  const char* bl2 = smem + 2*(size_t)GS*2 + b_lane;
  constexpr int GK0_L0 = 24;   // k-group1 start kstep, layer0
  constexpr int GK0_L1 = 32;   // layer1

  unsigned lgen = 0;
  float zreg[4] = {0,0,0,0};

  for (int iter = 0; iter <= SEQ; ++iter){
    const int  t    = (LAYER==0) ? iter : (iter-1);
    const bool act  = (LAYER==0) ? (iter < SEQ) : (iter >= 1);
    const int  bufA = (iter & 1) ^ 1;     // buffer holding H0[t_needed]

    // ---------------- PHASE A : pre_r, pre_z ----------------
    f32x4 accr = {0,0,0,0}, accz = {0,0,0,0};
    if (act){
      if (LAYER==0){
        const f16* hsrc = h0_16 + (size_t)bufA*NB*HDIM;
        if (kg==0){
          const char* a1 = (const char*)(x16 + (size_t)t*NB*IDIM + a_off_x);
          const char* a2 = (const char*)(hsrc + a_off_h);
          gemm_frag<2,16,8>(a1,a2,bl0,bl1,accr,accz);
        } else {
          const char* a1 = (const char*)(hsrc + a_off_h + 256);
          gemm_frag<2,24,0>(a1,a1,bl0+GK0_L0*512,bl1+GK0_L0*512,accr,accz);
        }
      } else {
        if (kg==0){
          const char* a1 = (const char*)(h0_16 + (size_t)bufA*NB*HDIM + a_off_h);
          gemm_frag<2,32,0>(a1,a1,bl0,bl1,accr,accz);
        } else {
          const char* a1 = (const char*)(h1_16 + (size_t)(iter&1)*NB*HDIM + a_off_h);
          gemm_frag<2,32,0>(a1,a1,bl0+GK0_L1*512,bl1+GK0_L1*512,accr,accz);
        }
      }
      if (kg==1){
#pragma unroll
        for (int i=0;i<4;++i){
          sc[(i*4+mt)*64 + lane]     = accr[i];
          sc[((4+i)*4+mt)*64 + lane] = accz[i];
        }
      }
    }
    __syncthreads();
    if (act && kg==0){
#pragma unroll
      for (int i=0;i<4;++i){
        float r = sigf(accr[i] + sc[(i*4+mt)*64+lane]     + brv);
        float z = sigf(accz[i] + sc[((4+i)*4+mt)*64+lane] + bzv);
        zreg[i] = z;
        if (valid){
          int m = m0 + quad*4 + i;
          float hold = hf[(size_t)m*HDIM + col];
          hr[(size_t)m*HDIM + col] = (f16)(hold * r);
        }
      }
    }
    grid_barrier(bar, bar+32, 256u, lgen);

    // ---------------- PHASE B : candidate + h update ----------------
    f32x4 accc = {0,0,0,0}, dum = {0,0,0,0};
    if (act){
      if (LAYER==0){
        if (kg==0){
          const char* a1 = (const char*)(x16 + (size_t)t*NB*IDIM + a_off_x);
          const char* a2 = (const char*)(h0r + a_off_h);
          gemm_frag<1,16,8>(a1,a2,bl2,bl2,accc,dum);
        } else {
          const char* a1 = (const char*)(h0r + a_off_h + 256);
          gemm_frag<1,24,0>(a1,a1,bl2+GK0_L0*512,bl2,accc,dum);
        }
      } else {
        if (kg==0){
          const char* a1 = (const char*)(h0_16 + (size_t)bufA*NB*HDIM + a_off_h);
          gemm_frag<1,32,0>(a1,a1,bl2,bl2,accc,dum);
        } else {
          const char* a1 = (const char*)(h1r + a_off_h);
          gemm_frag<1,32,0>(a1,a1,bl2+GK0_L1*512,bl2,accc,dum);
        }
      }
      if (kg==1){
#pragma unroll
        for (int i=0;i<4;++i) sc[(i*4+mt)*64 + lane] = accc[i];
      }
    }
    __syncthreads();
    if (act && kg==0){
      const int bufW = (LAYER==0) ? (iter&1) : ((iter&1)^1);
#pragma unroll
      for (int i=0;i<4;++i){
        float can = tanh_fast(accc[i] + sc[(i*4+mt)*64+lane] + bcv);
        if (valid){
          int m = m0 + quad*4 + i;
          size_t o = (size_t)m*HDIM + col;
          float hold = hf[o];
          float hnew = hold*zreg[i] + (1.0f - zreg[i])*can;
          hf[o] = hnew;
          h16own[(size_t)bufW*NB*HDIM + o] = (f16)hnew;
        }
      }
    }
    grid_barrier(bar, bar+32, 256u, lgen);
  }
}

__global__ void __launch_bounds__(512, 2)
rnn_kernel(const float* x,
           const float* Wr0, const float* br0, const float* Wz0, const float* bz0,
           const float* Wc0, const float* bc0,
           const float* Wr1, const float* br1, const float* Wz1, const float* bz1,
           const float* Wc1, const float* bc1,
           const float* Wreg, const float* breg,
           float* out, char* ws){
  extern __shared__ char smem[];
  unsigned* bar = (unsigned*)(ws + OFF_BAR);
  const int layer = blockIdx.x & 1;
  const int idx   = blockIdx.x >> 1;

  if (layer==0) run_rnn<0>(idx, Wr0,br0,Wz0,bz0,Wc0,bc0, ws, smem, bar);
  else          run_rnn<1>(idx, Wr1,br1,Wz1,bz1,Wc1,bc1, ws, smem, bar);

  // final regressor: out[m][o] = h1[m] . Wreg[o] + breg[o]
  if (blockIdx.x == 0){
    const float* h1f = (const float*)(ws + OFF_H1F);
    int t2 = threadIdx.x;
    if (t2 < NB*2){
      int m = t2 >> 1, o = t2 & 1;
      const float* hp = h1f + (size_t)m*HDIM;
      const float* wp = Wreg + (size_t)o*HDIM;
      float acc = 0.f;
#pragma unroll 4
      for (int k=0;k<HDIM;k+=4){
        acc += hp[k]*wp[k] + hp[k+1]*wp[k+1] + hp[k+2]*wp[k+2] + hp[k+3]*wp[k+3];
      }
      out[t2] = acc + breg[o];
    }
  }
}

// x [B][S][I] fp32  ->  x16 [S][B][I] fp16
__global__ void prep_x(const float* x, f16* x16){
  size_t i = (size_t)blockIdx.x*256 + threadIdx.x;
  int ii = (int)(i & (IDIM-1));
  size_t r = i >> 9;            // = s*64 + b
  int b = (int)(r & (NB-1));
  int s = (int)(r >> 6);
  x16[i] = (f16)x[((size_t)b*SEQ + s)*IDIM + ii];
}

extern "C" void kernel_launch(void* const* d_in, const int* in_sizes, int n_in,
                              void* d_out, int out_size, void* d_ws, size_t ws_size,
                              hipStream_t stream){
  const float* x    = (const float*)d_in[0];
  const float* Wr0  = (const float*)d_in[1];
  const float* br0  = (const float*)d_in[2];
  const float* Wz0  = (const float*)d_in[3];
  const float* bz0  = (const float*)d_in[4];
  const float* Wc0  = (const float*)d_in[5];
  const float* bc0  = (const float*)d_in[6];
  const float* Wr1  = (const float*)d_in[7];
  const float* br1  = (const float*)d_in[8];
  const float* Wz1  = (const float*)d_in[9];
  const float* bz1  = (const float*)d_in[10];
  const float* Wc1  = (const float*)d_in[11];
  const float* bc1  = (const float*)d_in[12];
  const float* Wreg = (const float*)d_in[13];
  const float* breg = (const float*)d_in[14];
  float* out = (float*)d_out;
  char*  ws  = (char*)d_ws;

  // zero h buffers + barrier counters
  hipMemsetAsync(ws, 0, OFF_BAR + 256, stream);

  // convert x to fp16, [S][B][I]
  prep_x<<<(SEQ*NB*IDIM)/256, 256, 0, stream>>>(x, (f16*)(ws + OFF_X16));

  hipFuncSetAttribute((const void*)rnn_kernel,
                      hipFuncAttributeMaxDynamicSharedMemorySize, 160*1024);

  void* args[] = { (void*)&x,
                   (void*)&Wr0, (void*)&br0, (void*)&Wz0, (void*)&bz0,
                   (void*)&Wc0, (void*)&bc0,
                   (void*)&Wr1, (void*)&br1, (void*)&Wz1, (void*)&bz1,
                   (void*)&Wc1, (void*)&bc1,
                   (void*)&Wreg, (void*)&breg,
                   (void*)&out, (void*)&ws };
  hipLaunchCooperativeKernel((const void*)rnn_kernel, dim3(256), dim3(512),
                             args, (unsigned)SMEM_BYTES, stream);
}

// Round 3
// 17730.910 us; speedup vs baseline: 1.0702x; 1.0173x over previous
//
#include <hip/hip_runtime.h>

// ============================================================================
// 2-layer GRU RNN, persistent cooperative kernel. B=64, S=512, I=512, H=1024.
// Round 3:
//  - TREE grid barrier: 16 group counters (256B-spread lines) -> root -> gen,
//    monotonic counts, s_sleep backoff. Serial atomic chain 256 -> 16+16.
//  - A-fragments held in VGPRs across the intra-step barrier: phase B reuses
//    phase-A x-frags (L0) / h0-frags (L1). L1-kg0 phase B does zero loads.
//  - 512 thr/WG, K-split 2, LDS weights in MFMA-frag order (0 bank conflicts).
// ============================================================================

typedef _Float16 f16;
typedef f16  f16x8 __attribute__((ext_vector_type(8)));
typedef float f32x4 __attribute__((ext_vector_type(4)));

#define NB   64
#define SEQ  512
#define IDIM 512
#define HDIM 1024

// workspace layout (bytes)
#define OFF_H0   0u                      // f16 [2][64][1024]  = 262144
#define OFF_H1   262144u                 // f16 [2][64][1024]
#define OFF_H0R  524288u                 // f16 [64][1024]     = 131072
#define OFF_H1R  655360u                 // f16 [64][1024]
#define OFF_H0F  786432u                 // f32 [64][1024]     = 262144
#define OFF_H1F  1048576u                // f32 [64][1024]
#define OFF_BAR  1310720u                // barrier region (8 KB)
#define OFF_X16  1318912u                // f16 [512][64][512] = 33554432

// LDS: weights (3 gates, frag order, 512B/kstep) + 8KB reduction scratch
#define SMEM_BYTES (3*64*512 + 8192)     // 106496 (L1 worst case)

__device__ __forceinline__ float sigf(float x){ return 1.0f/(1.0f+__expf(-x)); }
__device__ __forceinline__ float tanh_fast(float x){ float e=__expf(2.0f*x); return 1.0f - 2.0f/(e+1.0f); }

// ---- tree barrier: 16 groups of 16 WGs -> root(16) -> gen. Monotonic. ----
// layout in barb: cnt[g] @ g*256 ; root @ 4096 ; gen @ 4352
__device__ __forceinline__ void grid_barrier(char* barb, unsigned& lgen){
  __syncthreads();
  if (threadIdx.x == 0){
    unsigned g = (unsigned)blockIdx.x & 15u;
    unsigned* cnt  = (unsigned*)(barb + g*256);
    unsigned* root = (unsigned*)(barb + 4096);
    unsigned* gen  = (unsigned*)(barb + 4352);
    const unsigned tgt = lgen + 1u;
    unsigned old = __hip_atomic_fetch_add(cnt, 1u, __ATOMIC_ACQ_REL, __HIP_MEMORY_SCOPE_AGENT);
    if (old == tgt*16u - 1u){
      unsigned r = __hip_atomic_fetch_add(root, 1u, __ATOMIC_ACQ_REL, __HIP_MEMORY_SCOPE_AGENT);
      if (r == tgt*16u - 1u){
        __hip_atomic_store(gen, tgt, __ATOMIC_RELEASE, __HIP_MEMORY_SCOPE_AGENT);
      }
    }
    while (__hip_atomic_load(gen, __ATOMIC_RELAXED, __HIP_MEMORY_SCOPE_AGENT) < tgt){
      __builtin_amdgcn_s_sleep(2);
    }
    (void)__hip_atomic_load(gen, __ATOMIC_ACQUIRE, __HIP_MEMORY_SCOPE_AGENT);
    lgen = tgt;
  }
  __syncthreads();
}

template<int N>
__device__ __forceinline__ void load_frags(f16x8* f, const f16* a){
  const char* p = (const char*)a;
#pragma unroll
  for (int j=0;j<N;++j) f[j] = *(const f16x8*)(p + j*64);
}

// MFMA over N held frags starting at global kstep KS0 (B stride 512B/kstep).
template<int NG, int N, int KS0>
__device__ __forceinline__ void mfma_run(const f16x8* f, const char* b0, const char* b1,
                                         f32x4& acc0, f32x4& acc1){
  __builtin_amdgcn_sched_barrier(0);
#pragma unroll
  for (int j=0;j<N;++j){
    f16x8 b0v = *(const f16x8*)(b0 + (KS0+j)*512);
    acc0 = __builtin_amdgcn_mfma_f32_16x16x32_f16(f[j], b0v, acc0, 0,0,0);
    if constexpr (NG==2){
      f16x8 b1v = *(const f16x8*)(b1 + (KS0+j)*512);
      acc1 = __builtin_amdgcn_mfma_f32_16x16x32_f16(f[j], b1v, acc1, 0,0,0);
    }
  }
}

template<int LAYER>
__device__ void run_rnn(int idx,
    const float* Wr, const float* brp, const float* Wz, const float* bzp,
    const float* Wc, const float* bcp, char* ws, char* smem, char* barb){
  constexpr int K   = (LAYER==0) ? (IDIM+HDIM) : (2*HDIM);   // 1536 / 2048
  constexpr int NKS = K/32;                                   // 48 / 64
  constexpr int GS  = NKS*256;                                // f16 per gate
  const int n0  = idx*8;
  const int tid = threadIdx.x;

  f16*   wl = (f16*)smem;
  float* sc = (float*)(smem + (size_t)3*GS*2);   // [8][4][64] f32 scratch

  // ---- weights -> LDS in MFMA frag order: wl[g][gk][quad][nloc][e] ----
  for (int g=0; g<3; ++g){
    const float* W = (g==0)? Wr : (g==1)? Wz : Wc;
#pragma unroll 1
    for (int i = tid; i < GS; i += 512){
      int gk   = i >> 8;
      int rem  = i & 255;
      int quad = rem >> 6;
      int rem2 = rem & 63;
      int nl   = rem2 >> 3;
      int e    = rem2 & 7;
      wl[(size_t)g*GS + i] = (f16)W[(size_t)(n0+nl)*K + gk*32 + quad*8 + e];
    }
  }
  __syncthreads();

  const int lane = tid & 63;
  const int wv   = tid >> 6;          // 0..7
  const int mt   = wv & 3;            // m-tile index
  const int kg   = wv >> 2;           // k-group
  const int m0   = mt*16;
  const int quad = lane >> 4;
  const int ncol = lane & 15;
  const int nloc = ncol & 7;
  const int col  = n0 + nloc;
  const bool valid = (ncol < 8);

  const float brv = brp[col], bzv = bzp[col], bcv = bcp[col];

  f16*   h0_16 = (f16*)(ws + OFF_H0);
  f16*   h1_16 = (f16*)(ws + OFF_H1);
  f16*   h0r   = (f16*)(ws + OFF_H0R);
  f16*   h1r   = (f16*)(ws + OFF_H1R);
  float* hf    = (float*)(ws + (LAYER==0 ? OFF_H0F : OFF_H1F));
  const f16* x16 = (const f16*)(ws + OFF_X16);
  f16*   hr      = (LAYER==0) ? h0r : h1r;
  f16*   h16own  = (LAYER==0) ? h0_16 : h1_16;

  const int a_off_x = (m0 + ncol)*IDIM + quad*8;
  const int a_off_h = (m0 + ncol)*HDIM + quad*8;

  // B frag base (lane part): byte addr quad*128 + nloc*16
  const size_t b_lane = (size_t)quad*128 + (size_t)nloc*16;
  const char* bl0 = smem + 0*(size_t)GS*2 + b_lane;
  const char* bl1 = smem + 1*(size_t)GS*2 + b_lane;
  const char* bl2 = smem + 2*(size_t)GS*2 + b_lane;

  unsigned lgen = 0;
  float zreg[4] = {0,0,0,0};
  f16x8 fA[32];                        // held A fragments (L0 uses 24)

  for (int iter = 0; iter <= SEQ; ++iter){
    const int  t    = (LAYER==0) ? iter : (iter-1);
    const bool act  = (LAYER==0) ? (iter < SEQ) : (iter >= 1);
    const int  bufA = (iter & 1) ^ 1;     // buffer holding H0[t_needed]

    // ---------------- PHASE A : pre_r, pre_z ----------------
    f32x4 accr = {0,0,0,0}, accz = {0,0,0,0};
    if (act){
      if (LAYER==0){
        const f16* hsrc = h0_16 + (size_t)bufA*NB*HDIM;
        if (kg==0){
          load_frags<16>(fA,    x16 + (size_t)t*NB*IDIM + a_off_x);
          load_frags<8> (fA+16, hsrc + a_off_h);
          mfma_run<2,24,0>(fA, bl0, bl1, accr, accz);
        } else {
          load_frags<24>(fA, hsrc + a_off_h + 256);
          mfma_run<2,24,24>(fA, bl0, bl1, accr, accz);
        }
      } else {
        if (kg==0){
          load_frags<32>(fA, h0_16 + (size_t)bufA*NB*HDIM + a_off_h);
          mfma_run<2,32,0>(fA, bl0, bl1, accr, accz);
        } else {
          load_frags<32>(fA, h1_16 + (size_t)(iter&1)*NB*HDIM + a_off_h);
          mfma_run<2,32,32>(fA, bl0, bl1, accr, accz);
        }
      }
      if (kg==1){
#pragma unroll
        for (int i=0;i<4;++i){
          sc[(i*4+mt)*64 + lane]     = accr[i];
          sc[((4+i)*4+mt)*64 + lane] = accz[i];
        }
      }
    }
    __syncthreads();
    if (act && kg==0){
#pragma unroll
      for (int i=0;i<4;++i){
        float r = sigf(accr[i] + sc[(i*4+mt)*64+lane]     + brv);
        float z = sigf(accz[i] + sc[((4+i)*4+mt)*64+lane] + bzv);
        zreg[i] = z;
        if (valid){
          int m = m0 + quad*4 + i;
          float hold = hf[(size_t)m*HDIM + col];
          hr[(size_t)m*HDIM + col] = (f16)(hold * r);
        }
      }
    }
    grid_barrier(barb, lgen);

    // ---------------- PHASE B : candidate + h update ----------------
    f32x4 accc = {0,0,0,0}, dum = {0,0,0,0};
    if (act){
      if (LAYER==0){
        if (kg==0){
          load_frags<8>(fA+16, h0r + a_off_h);        // x frags 0..15 held
          mfma_run<1,24,0>(fA, bl2, bl2, accc, dum);
        } else {
          load_frags<24>(fA, h0r + a_off_h + 256);
          mfma_run<1,24,24>(fA, bl2, bl2, accc, dum);
        }
      } else {
        if (kg==0){
          // all 32 h0 frags held from phase A — zero loads
          mfma_run<1,32,0>(fA, bl2, bl2, accc, dum);
        } else {
          load_frags<32>(fA, h1r + a_off_h);
          mfma_run<1,32,32>(fA, bl2, bl2, accc, dum);
        }
      }
      if (kg==1){
#pragma unroll
        for (int i=0;i<4;++i) sc[(i*4+mt)*64 + lane] = accc[i];
      }
    }
    __syncthreads();
    if (act && kg==0){
      const int bufW = (LAYER==0) ? (iter&1) : ((iter&1)^1);
#pragma unroll
      for (int i=0;i<4;++i){
        float can = tanh_fast(accc[i] + sc[(i*4+mt)*64+lane] + bcv);
        if (valid){
          int m = m0 + quad*4 + i;
          size_t o = (size_t)m*HDIM + col;
          float hold = hf[o];
          float hnew = hold*zreg[i] + (1.0f - zreg[i])*can;
          hf[o] = hnew;
          h16own[(size_t)bufW*NB*HDIM + o] = (f16)hnew;
        }
      }
    }
    grid_barrier(barb, lgen);
  }
}

__global__ void __launch_bounds__(512, 2)
rnn_kernel(const float* x,
           const float* Wr0, const float* br0, const float* Wz0, const float* bz0,
           const float* Wc0, const float* bc0,
           const float* Wr1, const float* br1, const float* Wz1, const float* bz1,
           const float* Wc1, const float* bc1,
           const float* Wreg, const float* breg,
           float* out, char* ws){
  extern __shared__ char smem[];
  char* barb = ws + OFF_BAR;
  const int layer = blockIdx.x & 1;
  const int idx   = blockIdx.x >> 1;

  if (layer==0) run_rnn<0>(idx, Wr0,br0,Wz0,bz0,Wc0,bc0, ws, smem, barb);
  else          run_rnn<1>(idx, Wr1,br1,Wz1,bz1,Wc1,bc1, ws, smem, barb);

  // final regressor: out[m][o] = h1[m] . Wreg[o] + breg[o]
  if (blockIdx.x == 0){
    const float* h1f = (const float*)(ws + OFF_H1F);
    int t2 = threadIdx.x;
    if (t2 < NB*2){
      int m = t2 >> 1, o = t2 & 1;
      const float* hp = h1f + (size_t)m*HDIM;
      const float* wp = Wreg + (size_t)o*HDIM;
      float acc = 0.f;
#pragma unroll 4
      for (int k=0;k<HDIM;k+=4){
        acc += hp[k]*wp[k] + hp[k+1]*wp[k+1] + hp[k+2]*wp[k+2] + hp[k+3]*wp[k+3];
      }
      out[t2] = acc + breg[o];
    }
  }
}

// x [B][S][I] fp32  ->  x16 [S][B][I] fp16
__global__ void prep_x(const float* x, f16* x16){
  size_t i = (size_t)blockIdx.x*256 + threadIdx.x;
  int ii = (int)(i & (IDIM-1));
  size_t r = i >> 9;            // = s*64 + b
  int b = (int)(r & (NB-1));
  int s = (int)(r >> 6);
  x16[i] = (f16)x[((size_t)b*SEQ + s)*IDIM + ii];
}

extern "C" void kernel_launch(void* const* d_in, const int* in_sizes, int n_in,
                              void* d_out, int out_size, void* d_ws, size_t ws_size,
                              hipStream_t stream){
  const float* x    = (const float*)d_in[0];
  const float* Wr0  = (const float*)d_in[1];
  const float* br0  = (const float*)d_in[2];
  const float* Wz0  = (const float*)d_in[3];
  const float* bz0  = (const float*)d_in[4];
  const float* Wc0  = (const float*)d_in[5];
  const float* bc0  = (const float*)d_in[6];
  const float* Wr1  = (const float*)d_in[7];
  const float* br1  = (const float*)d_in[8];
  const float* Wz1  = (const float*)d_in[9];
  const float* bz1  = (const float*)d_in[10];
  const float* Wc1  = (const float*)d_in[11];
  const float* bc1  = (const float*)d_in[12];
  const float* Wreg = (const float*)d_in[13];
  const float* breg = (const float*)d_in[14];
  float* out = (float*)d_out;
  char*  ws  = (char*)d_ws;

  // zero h buffers + barrier region
  hipMemsetAsync(ws, 0, OFF_BAR + 8192, stream);

  // convert x to fp16, [S][B][I]
  prep_x<<<(SEQ*NB*IDIM)/256, 256, 0, stream>>>(x, (f16*)(ws + OFF_X16));

  hipFuncSetAttribute((const void*)rnn_kernel,
                      hipFuncAttributeMaxDynamicSharedMemorySize, 160*1024);

  void* args[] = { (void*)&x,
                   (void*)&Wr0, (void*)&br0, (void*)&Wz0, (void*)&bz0,
                   (void*)&Wc0, (void*)&bc0,
                   (void*)&Wr1, (void*)&br1, (void*)&Wz1, (void*)&bz1,
                   (void*)&Wc1, (void*)&bc1,
                   (void*)&Wreg, (void*)&breg,
                   (void*)&out, (void*)&ws };
  hipLaunchCooperativeKernel((const void*)rnn_kernel, dim3(256), dim3(512),
                             args, (unsigned)SMEM_BYTES, stream);
}

// Round 4
// 14709.608 us; speedup vs baseline: 1.2900x; 1.2054x over previous
//
#include <hip/hip_runtime.h>

// ============================================================================
// 2-layer GRU RNN, persistent cooperative kernel. B=64, S=512, I=512, H=1024.
// Round 4: NO cache maintenance in steady state.
//  - All barrier atomics RELAXED at agent scope (no buffer_wbl2 / buffer_inv,
//    which an ACQ_REL agent atomic forces on gfx950 and which walked the 4MB
//    L2 twice per step = the ~34us/step plateau of R1-R3).
//  - Ordering done manually: s_waitcnt(0) in every wave before barrier
//    arrival; barrier flags + shared h data live at LLC (L2-bypassed).
//  - Shared h buffers: loads via relaxed agent-scope 8B atomic loads
//    (sc0 sc1, compiler-tracked, pipelineable); stores via inline-asm
//    global_store_short sc0 sc1. No L2 copies -> never stale.
//  - x16/weights/biases read-only cached; fp32 master h is WG-private cached.
//    L2 now stays warm across steps.
// ============================================================================

typedef _Float16 f16;
typedef f16  f16x8 __attribute__((ext_vector_type(8)));
typedef float f32x4 __attribute__((ext_vector_type(4)));
typedef unsigned long long u64;

#define NB   64
#define SEQ  512
#define IDIM 512
#define HDIM 1024

// workspace layout (bytes)
#define OFF_H0   0u                      // f16 [2][64][1024]  = 262144  (coherent)
#define OFF_H1   262144u                 // f16 [2][64][1024]            (coherent)
#define OFF_H0R  524288u                 // f16 [64][1024]     = 131072  (coherent)
#define OFF_H1R  655360u                 // f16 [64][1024]               (coherent)
#define OFF_H0F  786432u                 // f32 [64][1024]  (WG-private, cached)
#define OFF_H1F  1048576u                // f32 [64][1024]
#define OFF_BAR  1310720u                // barrier region (8 KB, LLC atomics)
#define OFF_X16  1318912u                // f16 [512][64][512] = 33554432 (cached)

// LDS: weights (3 gates, frag order, 512B/kstep) + 8KB reduction scratch
#define SMEM_BYTES (3*64*512 + 8192)     // 106496 (L1 worst case)

__device__ __forceinline__ float sigf(float x){ return 1.0f/(1.0f+__expf(-x)); }
__device__ __forceinline__ float tanh_fast(float x){ float e=__expf(2.0f*x); return 1.0f - 2.0f/(e+1.0f); }

// coherent 16B load as two 8B relaxed agent-scope atomic loads (sc0 sc1,
// bypass L1/L2, read LLC; compiler tracks vmcnt so they pipeline)
__device__ __forceinline__ f16x8 cload16(const f16* p){
  u64 lo = __hip_atomic_load((const u64*)p,       __ATOMIC_RELAXED, __HIP_MEMORY_SCOPE_AGENT);
  u64 hi = __hip_atomic_load(((const u64*)p) + 1, __ATOMIC_RELAXED, __HIP_MEMORY_SCOPE_AGENT);
  union { u64 q[2]; f16x8 v; } u;
  u.q[0]=lo; u.q[1]=hi;
  return u.v;
}

// coherent 2B store, write-through to LLC (completion guaranteed by the
// s_waitcnt(0) each wave executes before barrier arrival)
__device__ __forceinline__ void cstore2(f16* p, f16 v){
  unsigned short s = __builtin_bit_cast(unsigned short, v);
  asm volatile("global_store_short %0, %1, off sc0 sc1" :: "v"(p), "v"(s) : "memory");
}

// ---- tree barrier: 16 groups of 16 WGs -> root(16) -> gen. Monotonic,
// ALL RELAXED (no cache maintenance). Wave-level waitcnt drains stores first.
__device__ __forceinline__ void grid_barrier(char* barb, unsigned& lgen){
  __builtin_amdgcn_s_waitcnt(0);           // drain this wave's coherent stores
  __syncthreads();                          // all waves of WG drained
  if (threadIdx.x == 0){
    unsigned g = (unsigned)blockIdx.x & 15u;
    unsigned* cnt  = (unsigned*)(barb + g*256);
    unsigned* root = (unsigned*)(barb + 4096);
    unsigned* gen  = (unsigned*)(barb + 4352);
    const unsigned tgt = lgen + 1u;
    unsigned old = __hip_atomic_fetch_add(cnt, 1u, __ATOMIC_RELAXED, __HIP_MEMORY_SCOPE_AGENT);
    if (old == tgt*16u - 1u){
      unsigned r = __hip_atomic_fetch_add(root, 1u, __ATOMIC_RELAXED, __HIP_MEMORY_SCOPE_AGENT);
      if (r == tgt*16u - 1u){
        __hip_atomic_store(gen, tgt, __ATOMIC_RELAXED, __HIP_MEMORY_SCOPE_AGENT);
      }
    }
    while (__hip_atomic_load(gen, __ATOMIC_RELAXED, __HIP_MEMORY_SCOPE_AGENT) < tgt){
      __builtin_amdgcn_s_sleep(2);
    }
    lgen = tgt;
  }
  __syncthreads();
}

template<int N, bool COH>
__device__ __forceinline__ void load_frags(f16x8* f, const f16* a){
#pragma unroll
  for (int j=0;j<N;++j){
    if constexpr (COH) f[j] = cload16(a + j*32);
    else               f[j] = *(const f16x8*)((const char*)a + j*64);
  }
}

// MFMA over N held frags starting at global kstep KS0 (B stride 512B/kstep).
template<int NG, int N, int KS0>
__device__ __forceinline__ void mfma_run(const f16x8* f, const char* b0, const char* b1,
                                         f32x4& acc0, f32x4& acc1){
  __builtin_amdgcn_sched_barrier(0);
#pragma unroll
  for (int j=0;j<N;++j){
    f16x8 b0v = *(const f16x8*)(b0 + (KS0+j)*512);
    acc0 = __builtin_amdgcn_mfma_f32_16x16x32_f16(f[j], b0v, acc0, 0,0,0);
    if constexpr (NG==2){
      f16x8 b1v = *(const f16x8*)(b1 + (KS0+j)*512);
      acc1 = __builtin_amdgcn_mfma_f32_16x16x32_f16(f[j], b1v, acc1, 0,0,0);
    }
  }
}

template<int LAYER>
__device__ void run_rnn(int idx,
    const float* Wr, const float* brp, const float* Wz, const float* bzp,
    const float* Wc, const float* bcp, char* ws, char* smem, char* barb){
  constexpr int K   = (LAYER==0) ? (IDIM+HDIM) : (2*HDIM);   // 1536 / 2048
  constexpr int NKS = K/32;                                   // 48 / 64
  constexpr int GS  = NKS*256;                                // f16 per gate
  const int n0  = idx*8;
  const int tid = threadIdx.x;

  f16*   wl = (f16*)smem;
  float* sc = (float*)(smem + (size_t)3*GS*2);   // [8][4][64] f32 scratch

  // ---- weights -> LDS in MFMA frag order: wl[g][gk][quad][nloc][e] ----
  for (int g=0; g<3; ++g){
    const float* W = (g==0)? Wr : (g==1)? Wz : Wc;
#pragma unroll 1
    for (int i = tid; i < GS; i += 512){
      int gk   = i >> 8;
      int rem  = i & 255;
      int quad = rem >> 6;
      int rem2 = rem & 63;
      int nl   = rem2 >> 3;
      int e    = rem2 & 7;
      wl[(size_t)g*GS + i] = (f16)W[(size_t)(n0+nl)*K + gk*32 + quad*8 + e];
    }
  }
  __syncthreads();

  const int lane = tid & 63;
  const int wv   = tid >> 6;          // 0..7
  const int mt   = wv & 3;            // m-tile index
  const int kg   = wv >> 2;           // k-group
  const int m0   = mt*16;
  const int quad = lane >> 4;
  const int ncol = lane & 15;
  const int nloc = ncol & 7;
  const int col  = n0 + nloc;
  const bool valid = (ncol < 8);

  const float brv = brp[col], bzv = bzp[col], bcv = bcp[col];

  f16*   h0_16 = (f16*)(ws + OFF_H0);
  f16*   h1_16 = (f16*)(ws + OFF_H1);
  f16*   h0r   = (f16*)(ws + OFF_H0R);
  f16*   h1r   = (f16*)(ws + OFF_H1R);
  float* hf    = (float*)(ws + (LAYER==0 ? OFF_H0F : OFF_H1F));
  const f16* x16 = (const f16*)(ws + OFF_X16);
  f16*   hr      = (LAYER==0) ? h0r : h1r;
  f16*   h16own  = (LAYER==0) ? h0_16 : h1_16;

  const int a_off_x = (m0 + ncol)*IDIM + quad*8;
  const int a_off_h = (m0 + ncol)*HDIM + quad*8;

  // B frag base (lane part): byte addr quad*128 + nloc*16
  const size_t b_lane = (size_t)quad*128 + (size_t)nloc*16;
  const char* bl0 = smem + 0*(size_t)GS*2 + b_lane;
  const char* bl1 = smem + 1*(size_t)GS*2 + b_lane;
  const char* bl2 = smem + 2*(size_t)GS*2 + b_lane;

  unsigned lgen = 0;
  float zreg[4] = {0,0,0,0};
  f16x8 fA[32];                        // held A fragments (L0 uses 24)

  for (int iter = 0; iter <= SEQ; ++iter){
    const int  t    = (LAYER==0) ? iter : (iter-1);
    const bool act  = (LAYER==0) ? (iter < SEQ) : (iter >= 1);
    const int  bufA = (iter & 1) ^ 1;     // buffer holding H0[t_needed]

    // ---------------- PHASE A : pre_r, pre_z ----------------
    f32x4 accr = {0,0,0,0}, accz = {0,0,0,0};
    if (act){
      if (LAYER==0){
        const f16* hsrc = h0_16 + (size_t)bufA*NB*HDIM;
        if (kg==0){
          load_frags<16,false>(fA,    x16 + (size_t)t*NB*IDIM + a_off_x);
          load_frags<8, true >(fA+16, hsrc + a_off_h);
          mfma_run<2,24,0>(fA, bl0, bl1, accr, accz);
        } else {
          load_frags<24,true>(fA, hsrc + a_off_h + 256);
          mfma_run<2,24,24>(fA, bl0, bl1, accr, accz);
        }
      } else {
        if (kg==0){
          load_frags<32,true>(fA, h0_16 + (size_t)bufA*NB*HDIM + a_off_h);
          mfma_run<2,32,0>(fA, bl0, bl1, accr, accz);
        } else {
          load_frags<32,true>(fA, h1_16 + (size_t)(iter&1)*NB*HDIM + a_off_h);
          mfma_run<2,32,32>(fA, bl0, bl1, accr, accz);
        }
      }
      if (kg==1){
#pragma unroll
        for (int i=0;i<4;++i){
          sc[(i*4+mt)*64 + lane]     = accr[i];
          sc[((4+i)*4+mt)*64 + lane] = accz[i];
        }
      }
    }
    __syncthreads();
    if (act && kg==0){
#pragma unroll
      for (int i=0;i<4;++i){
        float r = sigf(accr[i] + sc[(i*4+mt)*64+lane]     + brv);
        float z = sigf(accz[i] + sc[((4+i)*4+mt)*64+lane] + bzv);
        zreg[i] = z;
        if (valid){
          int m = m0 + quad*4 + i;
          float hold = hf[(size_t)m*HDIM + col];
          cstore2(hr + (size_t)m*HDIM + col, (f16)(hold * r));
        }
      }
    }
    grid_barrier(barb, lgen);

    // ---------------- PHASE B : candidate + h update ----------------
    f32x4 accc = {0,0,0,0}, dum = {0,0,0,0};
    if (act){
      if (LAYER==0){
        if (kg==0){
          load_frags<8,true>(fA+16, h0r + a_off_h);   // x frags 0..15 held
          mfma_run<1,24,0>(fA, bl2, bl2, accc, dum);
        } else {
          load_frags<24,true>(fA, h0r + a_off_h + 256);
          mfma_run<1,24,24>(fA, bl2, bl2, accc, dum);
        }
      } else {
        if (kg==0){
          // all 32 h0 frags held from phase A — zero loads
          mfma_run<1,32,0>(fA, bl2, bl2, accc, dum);
        } else {
          load_frags<32,true>(fA, h1r + a_off_h);
          mfma_run<1,32,32>(fA, bl2, bl2, accc, dum);
        }
      }
      if (kg==1){
#pragma unroll
        for (int i=0;i<4;++i) sc[(i*4+mt)*64 + lane] = accc[i];
      }
    }
    __syncthreads();
    if (act && kg==0){
      const int bufW = (LAYER==0) ? (iter&1) : ((iter&1)^1);
#pragma unroll
      for (int i=0;i<4;++i){
        float can = tanh_fast(accc[i] + sc[(i*4+mt)*64+lane] + bcv);
        if (valid){
          int m = m0 + quad*4 + i;
          size_t o = (size_t)m*HDIM + col;
          float hold = hf[o];
          float hnew = hold*zreg[i] + (1.0f - zreg[i])*can;
          hf[o] = hnew;                                    // private, cached
          cstore2(h16own + (size_t)bufW*NB*HDIM + o, (f16)hnew);
        }
      }
    }
    grid_barrier(barb, lgen);
  }
}

__global__ void __launch_bounds__(512, 2)
rnn_kernel(const float* x,
           const float* Wr0, const float* br0, const float* Wz0, const float* bz0,
           const float* Wc0, const float* bc0,
           const float* Wr1, const float* br1, const float* Wz1, const float* bz1,
           const float* Wc1, const float* bc1,
           const float* Wreg, const float* breg,
           float* out, char* ws){
  extern __shared__ char smem[];
  char* barb = ws + OFF_BAR;
  const int layer = blockIdx.x & 1;
  const int idx   = blockIdx.x >> 1;

  if (layer==0) run_rnn<0>(idx, Wr0,br0,Wz0,bz0,Wc0,bc0, ws, smem, barb);
  else          run_rnn<1>(idx, Wr1,br1,Wz1,bz1,Wc1,bc1, ws, smem, barb);

  // final regressor reads the coherent fp16 h1 mirror (buf 1 holds t=511).
  if (blockIdx.x == 0){
    const f16* h1c = (const f16*)(ws + OFF_H1) + (size_t)NB*HDIM;  // buf 1
    const float* Wreg_ = Wreg;
    int t2 = threadIdx.x;
    if (t2 < NB*2){
      int m = t2 >> 1, o = t2 & 1;
      const f16* hp = h1c + (size_t)m*HDIM;
      const float* wp = Wreg_ + (size_t)o*HDIM;
      float acc = 0.f;
#pragma unroll 4
      for (int k=0;k<HDIM;k+=4){
        u64 q = __hip_atomic_load((const u64*)(hp+k), __ATOMIC_RELAXED, __HIP_MEMORY_SCOPE_AGENT);
        union { u64 qq; f16 h[4]; } u; u.qq = q;
        acc += (float)u.h[0]*wp[k]   + (float)u.h[1]*wp[k+1]
             + (float)u.h[2]*wp[k+2] + (float)u.h[3]*wp[k+3];
      }
      out[t2] = acc + breg[o];
    }
  }
}

// x [B][S][I] fp32  ->  x16 [S][B][I] fp16
__global__ void prep_x(const float* x, f16* x16){
  size_t i = (size_t)blockIdx.x*256 + threadIdx.x;
  int ii = (int)(i & (IDIM-1));
  size_t r = i >> 9;            // = s*64 + b
  int b = (int)(r & (NB-1));
  int s = (int)(r >> 6);
  x16[i] = (f16)x[((size_t)b*SEQ + s)*IDIM + ii];
}

extern "C" void kernel_launch(void* const* d_in, const int* in_sizes, int n_in,
                              void* d_out, int out_size, void* d_ws, size_t ws_size,
                              hipStream_t stream){
  const float* x    = (const float*)d_in[0];
  const float* Wr0  = (const float*)d_in[1];
  const float* br0  = (const float*)d_in[2];
  const float* Wz0  = (const float*)d_in[3];
  const float* bz0  = (const float*)d_in[4];
  const float* Wc0  = (const float*)d_in[5];
  const float* bc0  = (const float*)d_in[6];
  const float* Wr1  = (const float*)d_in[7];
  const float* br1  = (const float*)d_in[8];
  const float* Wz1  = (const float*)d_in[9];
  const float* bz1  = (const float*)d_in[10];
  const float* Wc1  = (const float*)d_in[11];
  const float* bc1  = (const float*)d_in[12];
  const float* Wreg = (const float*)d_in[13];
  const float* breg = (const float*)d_in[14];
  float* out = (float*)d_out;
  char*  ws  = (char*)d_ws;

  // zero h buffers + barrier region
  hipMemsetAsync(ws, 0, OFF_BAR + 8192, stream);

  // convert x to fp16, [S][B][I]
  prep_x<<<(SEQ*NB*IDIM)/256, 256, 0, stream>>>(x, (f16*)(ws + OFF_X16));

  hipFuncSetAttribute((const void*)rnn_kernel,
                      hipFuncAttributeMaxDynamicSharedMemorySize, 160*1024);

  void* args[] = { (void*)&x,
                   (void*)&Wr0, (void*)&br0, (void*)&Wz0, (void*)&bz0,
                   (void*)&Wc0, (void*)&bc0,
                   (void*)&Wr1, (void*)&br1, (void*)&Wz1, (void*)&bz1,
                   (void*)&Wc1, (void*)&bc1,
                   (void*)&Wreg, (void*)&breg,
                   (void*)&out, (void*)&ws };
  hipLaunchCooperativeKernel((const void*)rnn_kernel, dim3(256), dim3(512),
                             args, (unsigned)SMEM_BYTES, stream);
}

// Round 6
// 6415.781 us; speedup vs baseline: 2.9576x; 2.2927x over previous
//
#include <hip/hip_runtime.h>

// ============================================================================
// 2-layer GRU RNN, persistent cooperative kernel. B=64, S=512, I=512, H=1024.
// Round 6: == Round 5 with LDS overflow fixed (SMEM_BYTES 36864 -> 37888;
//          the fp32 master-h array's rows 8..15 were beyond the allocation).
// Design: batch(4 groups of 16 rows) x N(32 slices of 32 cols) x layer(2)
//         = 256 WGs of 512 threads. Coherent traffic ~21 MB/step, read as
//         16B asm sc0sc1 loads. Weights streamed from (XCD-packed,
//         L2-resident) fp16 frag buffer. fp32 master h in LDS.
//         4 independent 64-WG barrier groups, all-relaxed atomics.
// ============================================================================

typedef _Float16 f16;
typedef f16  f16x8 __attribute__((ext_vector_type(8)));
typedef float f32x4 __attribute__((ext_vector_type(4)));
typedef unsigned long long u64;

#define NB   64
#define SEQ  512
#define IDIM 512
#define HDIM 1024
#define NBH  (NB*HDIM)          // 65536 elems per h snapshot

// workspace layout (bytes)
#define OFF_H0   0u             // f16 [2][64][1024] = 262144  (coherent mirror)
#define OFF_H1   262144u        // f16 [2][64][1024]
#define OFF_H0R  524288u        // f16 [64][1024]    = 131072  (h*r broadcast)
#define OFF_H1R  655360u        // f16 [64][1024]
#define OFF_BAR  786432u        // 4 groups x 1KB (cnt @ +0, gen @ +256)
#define OFF_W16  790528u        // f16 frag-order weights, L0 then L1
#define W16_L0_ELEMS 4718592u   // 3*1024*1536 (L1 starts here)

#define SMEM_BYTES 37888        // red 32K | zst 2K | hst 1K | hf 2K  (exact)

__device__ __forceinline__ float sigf(float x){ return 1.0f/(1.0f+__expf(-x)); }
__device__ __forceinline__ float tanh_fast(float x){ float e=__expf(2.0f*x); return 1.0f - 2.0f/(e+1.0f); }

// 16B coherent load: bypasses L1+L2 (system scope), reads LLC. NOT compiler
// vmcnt-tracked -> batch loads then one explicit s_waitcnt vmcnt(0).
__device__ __forceinline__ f16x8 cload16(const f16* p){
  f16x8 r;
  asm volatile("global_load_dwordx4 %0, %1, off sc0 sc1" : "=v"(r) : "v"(p));
  return r;
}
// 8B coherent write-through store
__device__ __forceinline__ void cstore8(f16* p, u64 v){
  asm volatile("global_store_dwordx2 %0, %1, off sc0 sc1" :: "v"(p), "v"(v) : "memory");
}

// x fp32 -> f16 fragment (plain cached loads; x is read-only)
__device__ __forceinline__ f16x8 load_x_frag(const float* p){
  f32x4 v0 = *(const f32x4*)p;
  f32x4 v1 = *(const f32x4*)(p+4);
  f16x8 r;
  r[0]=(f16)v0[0]; r[1]=(f16)v0[1]; r[2]=(f16)v0[2]; r[3]=(f16)v0[3];
  r[4]=(f16)v1[0]; r[5]=(f16)v1[1]; r[6]=(f16)v1[2]; r[7]=(f16)v1[3];
  return r;
}

// flat 64-WG barrier, monotonic, all-relaxed (no cache maintenance)
__device__ __forceinline__ void group_barrier(char* gb, unsigned& lgen){
  asm volatile("s_waitcnt vmcnt(0) lgkmcnt(0)" ::: "memory");
  __syncthreads();
  if (threadIdx.x == 0){
    unsigned* cnt = (unsigned*)gb;
    unsigned* gen = (unsigned*)(gb + 256);
    const unsigned tgt = lgen + 1u;
    unsigned old = __hip_atomic_fetch_add(cnt, 1u, __ATOMIC_RELAXED, __HIP_MEMORY_SCOPE_AGENT);
    if (old == tgt*64u - 1u){
      __hip_atomic_store(gen, tgt, __ATOMIC_RELAXED, __HIP_MEMORY_SCOPE_AGENT);
    }
    while (__hip_atomic_load(gen, __ATOMIC_RELAXED, __HIP_MEMORY_SCOPE_AGENT) < tgt){
      __builtin_amdgcn_s_sleep(2);
    }
    lgen = tgt;
  }
  __syncthreads();
}

template<int LAYER>
__device__ void run_rnn(int g, int n32, const float* x,
    const float* brp, const float* bzp, const float* bcp,
    char* ws, char* smem, char* gb){
  constexpr int K   = (LAYER==0) ? 1536 : 2048;
  constexpr int NKS = K/32;          // 48 | 64 ksteps
  constexpr int KW  = NKS/8;         // 6 | 8 ksteps per wave (kg-split 8)
  const int tid  = threadIdx.x;
  const int lane = tid & 63;
  const int kg   = tid >> 6;         // wave index = k-group 0..7
  const int quad = lane >> 4;
  const int qo   = quad*8;
  const int m_base = g*16;
  const int n_base = n32*32;
  const int arow   = m_base + (lane & 15);

  f32x4* red = (f32x4*)smem;                 // [4][8][64] f32x4 = 32768 B
  float* zst = (float*)(smem + 32768);       // [16][32] f32 = 2048 B
  f16*   hst = (f16*)  (smem + 34816);       // [16][32] f16 = 1024 B
  float* hf  = (float*)(smem + 35840);       // [16][32] f32 = 2048 B (ends 37888)

  hf[tid & 511] = 0.f;                       // 512 threads, 512 elems
  __syncthreads();

  f16* h0m = (f16*)(ws + OFF_H0);
  f16* h1m = (f16*)(ws + OFF_H1);
  f16* h0r = (f16*)(ws + OFF_H0R);
  f16* h1r = (f16*)(ws + OFF_H1R);
  f16* hrbuf = (LAYER==0)? h0r : h1r;
  f16* hown  = (LAYER==0)? h0m : h1m;
  const char* w16L = ws + OFF_W16 + (LAYER ? (size_t)W16_L0_ELEMS*2 : 0);

  // weight fragment base pointers: [gate][ntile][kstep][lane*16B], 1KB/kstep
  const size_t lo = (size_t)lane*16;
  const int nt0 = n32*2, nt1 = n32*2 + 1;
  const char* bR0 = w16L + ((size_t)((0*64 + nt0)*NKS + kg*KW))*1024 + lo;
  const char* bR1 = w16L + ((size_t)((0*64 + nt1)*NKS + kg*KW))*1024 + lo;
  const char* bZ0 = w16L + ((size_t)((1*64 + nt0)*NKS + kg*KW))*1024 + lo;
  const char* bZ1 = w16L + ((size_t)((1*64 + nt1)*NKS + kg*KW))*1024 + lo;
  const char* bC0 = w16L + ((size_t)((2*64 + nt0)*NKS + kg*KW))*1024 + lo;
  const char* bC1 = w16L + ((size_t)((2*64 + nt1)*NKS + kg*KW))*1024 + lo;

  // per-lane bias for this wave's owner role (ntile = kg&1)
  const int col_own = n_base + (kg & 1)*16 + (lane & 15);
  const float bRv = brp[col_own], bZv = bzp[col_own], bCv = bcp[col_own];

  unsigned lgen = 0;
  f16x8 fa[KW];

  for (int iter = 0; iter <= SEQ; ++iter){
    const int  t    = (LAYER==0) ? iter : (iter-1);
    const bool act  = (LAYER==0) ? (iter < SEQ) : (iter >= 1);
    const int  bufA = (iter & 1) ^ 1;

    // ================= PHASE A : pre_r, pre_z =================
    if (act){
#pragma unroll
      for (int j=0;j<KW;++j){
        int ks = kg*KW + j;
        if (LAYER==0){
          if (ks < 16)
            fa[j] = load_x_frag(x + ((size_t)arow*SEQ + t)*IDIM + ks*32 + qo);
          else
            fa[j] = cload16(h0m + (size_t)bufA*NBH + (size_t)arow*HDIM + (ks-16)*32 + qo);
        } else {
          if (ks < 32)
            fa[j] = cload16(h0m + (size_t)bufA*NBH + (size_t)arow*HDIM + ks*32 + qo);
          else
            fa[j] = cload16(h1m + (size_t)(iter&1)*NBH + (size_t)arow*HDIM + (ks-32)*32 + qo);
        }
      }
      asm volatile("s_waitcnt vmcnt(0)" ::: "memory");
      f32x4 aR0{0,0,0,0}, aR1{0,0,0,0}, aZ0{0,0,0,0}, aZ1{0,0,0,0};
#pragma unroll
      for (int j=0;j<KW;++j){
        aR0 = __builtin_amdgcn_mfma_f32_16x16x32_f16(fa[j], *(const f16x8*)(bR0 + j*1024), aR0,0,0,0);
        aR1 = __builtin_amdgcn_mfma_f32_16x16x32_f16(fa[j], *(const f16x8*)(bR1 + j*1024), aR1,0,0,0);
        aZ0 = __builtin_amdgcn_mfma_f32_16x16x32_f16(fa[j], *(const f16x8*)(bZ0 + j*1024), aZ0,0,0,0);
        aZ1 = __builtin_amdgcn_mfma_f32_16x16x32_f16(fa[j], *(const f16x8*)(bZ1 + j*1024), aZ1,0,0,0);
      }
      red[(0*8+kg)*64+lane] = aR0;  red[(1*8+kg)*64+lane] = aR1;
      red[(2*8+kg)*64+lane] = aZ0;  red[(3*8+kg)*64+lane] = aZ1;
    }
    __syncthreads();
    if (act && kg < 4){                      // owner waves: (gate, ntile)
      f32x4 s = red[(kg*8+0)*64+lane];
#pragma unroll
      for (int k2=1;k2<8;++k2) s += red[(kg*8+k2)*64+lane];
      const int coll = (kg&1)*16 + (lane&15);
#pragma unroll
      for (int i=0;i<4;++i){
        int rowl = quad*4 + i;
        if (kg < 2){                          // r gate -> h*r staged fp16
          float r = sigf(s[i] + bRv);
          hst[rowl*32 + coll] = (f16)(hf[rowl*32+coll] * r);
        } else {                              // z gate -> staged fp32
          zst[rowl*32 + coll] = sigf(s[i] + bZv);
        }
      }
    }
    __syncthreads();
    if (act && tid < 128){                    // publish h*r block (8B stores)
      int rowl = tid>>3, c8 = (tid&7)*4;
      u64 v = *(const u64*)(hst + rowl*32 + c8);
      cstore8(hrbuf + (size_t)(m_base+rowl)*HDIM + n_base + c8, v);
    }
    group_barrier(gb, lgen);

    // ================= PHASE B : candidate + h update =================
    if (act){
#pragma unroll
      for (int j=0;j<KW;++j){
        int ks = kg*KW + j;
        if (LAYER==0){
          if (ks >= 16)                       // x frags held from phase A
            fa[j] = cload16(h0r + (size_t)arow*HDIM + (ks-16)*32 + qo);
        } else {
          if (ks >= 32)                       // h0 frags held from phase A
            fa[j] = cload16(h1r + (size_t)arow*HDIM + (ks-32)*32 + qo);
        }
      }
      asm volatile("s_waitcnt vmcnt(0)" ::: "memory");
      f32x4 aC0{0,0,0,0}, aC1{0,0,0,0};
#pragma unroll
      for (int j=0;j<KW;++j){
        aC0 = __builtin_amdgcn_mfma_f32_16x16x32_f16(fa[j], *(const f16x8*)(bC0 + j*1024), aC0,0,0,0);
        aC1 = __builtin_amdgcn_mfma_f32_16x16x32_f16(fa[j], *(const f16x8*)(bC1 + j*1024), aC1,0,0,0);
      }
      red[(0*8+kg)*64+lane] = aC0;  red[(1*8+kg)*64+lane] = aC1;
    }
    __syncthreads();
    if (act && kg < 2){                       // owner waves: ntile = kg
      f32x4 s = red[(kg*8+0)*64+lane];
#pragma unroll
      for (int k2=1;k2<8;++k2) s += red[(kg*8+k2)*64+lane];
      const int coll = kg*16 + (lane&15);
#pragma unroll
      for (int i=0;i<4;++i){
        int rowl = quad*4 + i;
        float can = tanh_fast(s[i] + bCv);
        float z   = zst[rowl*32 + coll];
        float hnew = hf[rowl*32+coll]*z + (1.0f - z)*can;
        hf[rowl*32+coll]  = hnew;
        hst[rowl*32+coll] = (f16)hnew;
      }
    }
    __syncthreads();
    if (act && tid < 128){                    // publish h block
      const int bufW = (LAYER==0) ? (iter&1) : ((iter&1)^1);
      int rowl = tid>>3, c8 = (tid&7)*4;
      u64 v = *(const u64*)(hst + rowl*32 + c8);
      cstore8(hown + (size_t)bufW*NBH + (size_t)(m_base+rowl)*HDIM + n_base + c8, v);
    }
    group_barrier(gb, lgen);
  }
}

__global__ void __launch_bounds__(512, 2)
rnn_kernel(const float* x,
           const float* br0, const float* bz0, const float* bc0,
           const float* br1, const float* bz1, const float* bc1,
           const float* Wreg, const float* breg,
           float* out, char* ws){
  extern __shared__ char smem[];
  const int b = blockIdx.x;
  // XCD packing: same (layer,n32) pair's 4 batch-groups land on one XCD
  const int xcd = b & 7, slot = b >> 3;
  const int g = slot & 3, phi = slot >> 2;
  const int p = phi*8 + xcd;                  // 0..63 unique (layer, n32)
  const int layer = p >> 5, n32 = p & 31;
  char* gb = ws + OFF_BAR + (size_t)g*1024;

  if (layer==0) run_rnn<0>(g, n32, x, br0,bz0,bc0, ws, smem, gb);
  else          run_rnn<1>(g, n32, x, br1,bz1,bc1, ws, smem, gb);

  // regressor: one L1 WG per group handles its 16 rows (h1 final in buf 1)
  if (layer==1 && n32==0 && threadIdx.x < 32){
    int mrow = g*16 + ((int)threadIdx.x >> 1), o = threadIdx.x & 1;
    const f16* hp = (const f16*)(ws + OFF_H1) + (size_t)NBH + (size_t)mrow*HDIM;
    const float* wp = Wreg + (size_t)o*HDIM;
    float acc = 0.f;
#pragma unroll 4
    for (int k=0;k<HDIM;k+=4){
      u64 q = __hip_atomic_load((const u64*)(hp+k), __ATOMIC_RELAXED, __HIP_MEMORY_SCOPE_AGENT);
      union { u64 qq; f16 h[4]; } u; u.qq = q;
      acc += (float)u.h[0]*wp[k]   + (float)u.h[1]*wp[k+1]
           + (float)u.h[2]*wp[k+2] + (float)u.h[3]*wp[k+3];
    }
    out[mrow*2 + o] = acc + breg[o];
  }
}

// weights fp32 row-major [n][k] -> fp16 MFMA-frag order
// [layer][gate][ntile(64)][kstep][lane(64)][e(8)]; dst flat index == thread id
__global__ void prep_w(const float* Wr0, const float* Wz0, const float* Wc0,
                       const float* Wr1, const float* Wz1, const float* Wc1,
                       f16* w16){
  size_t i = (size_t)blockIdx.x*256 + threadIdx.x;
  const bool l1 = (i >= (size_t)W16_L0_ELEMS);
  size_t j = l1 ? i - (size_t)W16_L0_ELEMS : i;
  const int K   = l1 ? 2048 : 1536;
  const int NKS = K >> 5;
  int e    = (int)(j & 7);
  int lane = (int)((j >> 3) & 63);
  size_t r = j >> 9;
  int ks   = (int)(r % (size_t)NKS);
  size_t gnt = r / (size_t)NKS;
  int nt   = (int)(gnt & 63);
  int gate = (int)(gnt >> 6);
  int n = nt*16 + (lane & 15);
  int k = ks*32 + ((lane >> 4) << 3) + e;
  const float* W = l1 ? (gate==0 ? Wr1 : gate==1 ? Wz1 : Wc1)
                      : (gate==0 ? Wr0 : gate==1 ? Wz0 : Wc0);
  w16[i] = (f16)W[(size_t)n*K + k];
}

extern "C" void kernel_launch(void* const* d_in, const int* in_sizes, int n_in,
                              void* d_out, int out_size, void* d_ws, size_t ws_size,
                              hipStream_t stream){
  const float* x    = (const float*)d_in[0];
  const float* Wr0  = (const float*)d_in[1];
  const float* br0  = (const float*)d_in[2];
  const float* Wz0  = (const float*)d_in[3];
  const float* bz0  = (const float*)d_in[4];
  const float* Wc0  = (const float*)d_in[5];
  const float* bc0  = (const float*)d_in[6];
  const float* Wr1  = (const float*)d_in[7];
  const float* br1  = (const float*)d_in[8];
  const float* Wz1  = (const float*)d_in[9];
  const float* bz1  = (const float*)d_in[10];
  const float* Wc1  = (const float*)d_in[11];
  const float* bc1  = (const float*)d_in[12];
  const float* Wreg = (const float*)d_in[13];
  const float* breg = (const float*)d_in[14];
  float* out = (float*)d_out;
  char*  ws  = (char*)d_ws;

  // zero h mirrors + h*r buffers + barrier region
  hipMemsetAsync(ws, 0, OFF_W16, stream);

  // weights -> fp16 frag order (3*1024*1536 + 3*1024*2048 = 11010048 elems)
  prep_w<<<43008, 256, 0, stream>>>(Wr0, Wz0, Wc0, Wr1, Wz1, Wc1,
                                    (f16*)(ws + OFF_W16));

  hipFuncSetAttribute((const void*)rnn_kernel,
                      hipFuncAttributeMaxDynamicSharedMemorySize, 160*1024);

  void* args[] = { (void*)&x,
                   (void*)&br0, (void*)&bz0, (void*)&bc0,
                   (void*)&br1, (void*)&bz1, (void*)&bc1,
                   (void*)&Wreg, (void*)&breg,
                   (void*)&out, (void*)&ws };
  hipLaunchCooperativeKernel((const void*)rnn_kernel, dim3(256), dim3(512),
                             args, (unsigned)SMEM_BYTES, stream);
}